// Round 1
// baseline (27.619 us; speedup 1.0000x reference)
//
#include <hip/hip_runtime.h>

// Problem constants (fixed by the reference)
#define BB   32
#define NN   256
#define DD   3
#define HH   64
#define EPS  1e-6f

// f(d) / f'(d) lookup table
#define TABN   2048
#define DMAX   16.0f
#define DX     (DMAX / (float)(TABN - 1))
#define INV_DX ((float)(TABN - 1) / DMAX)

// ws layout: [tab: TABN*float2 = 16KB][v: 8192*3 f32 = 96KB][P: 8192 f32 = 32KB]
#define WS_V_OFF  (TABN * 8)
#define WS_P_OFF  (TABN * 8 + BB * NN * 3 * 4)

// ---------------------------------------------------------------------------
// Kernel 1: exact MLP (value + analytic d-derivative) at table nodes.
// 8 threads per node, each handling 8 of the 64 hidden-2 units.
// ---------------------------------------------------------------------------
__global__ __launch_bounds__(256) void build_table_kernel(
    const float* __restrict__ W1, const float* __restrict__ b1,
    const float* __restrict__ W2, const float* __restrict__ b2,
    const float* __restrict__ W3, const float* __restrict__ b3,
    const float* __restrict__ t,  float2* __restrict__ tab) {
  __shared__ float sW2[HH * HH];
  int tid = threadIdx.x;
  for (int i = tid; i < HH * HH; i += 256) sW2[i] = W2[i];
  __syncthreads();

  int gid  = blockIdx.x * 256 + tid;
  int node = gid >> 3;
  int sub  = gid & 7;
  if (node >= TABN) return;

  float d  = (float)node * DX;
  float tt = t[0];
  int   m0 = sub * 8;

  float u[8], w[8];
#pragma unroll
  for (int mm = 0; mm < 8; ++mm) { u[mm] = b2[m0 + mm]; w[mm] = 0.f; }

  for (int h = 0; h < HH; ++h) {
    float a  = W1[h];                                  // W1[0,h] (d coefficient)
    float z  = fmaf(a, d, fmaf(W1[HH + h], tt, b1[h])); // W1[1,h]*t + b1
    float th = tanhf(z);
    float g  = (1.f - th * th) * a;                    // dh1/dd
#pragma unroll
    for (int mm = 0; mm < 8; ++mm) {
      float wv = sW2[h * HH + m0 + mm];
      u[mm] = fmaf(th, wv, u[mm]);
      w[mm] = fmaf(g,  wv, w[mm]);
    }
  }

  float f = 0.f, fp = 0.f;
#pragma unroll
  for (int mm = 0; mm < 8; ++mm) {
    float th = tanhf(u[mm]);
    float w3 = W3[m0 + mm];
    f  = fmaf(th, w3, f);
    fp = fmaf((1.f - th * th) * w[mm], w3, fp);
  }
  // reduce across the 8 lanes of this node
#pragma unroll
  for (int off = 1; off < 8; off <<= 1) {
    f  += __shfl_xor(f,  off, 64);
    fp += __shfl_xor(fp, off, 64);
  }
  if (sub == 0) tab[node] = make_float2(f + b3[0], fp);
}

// ---------------------------------------------------------------------------
// Kernel 2: one wave per (b,i) row; 4 pairs per lane; Hermite-cubic table
// lookup for f and f'; wave-reduce v (3) and the trace partial.
// ---------------------------------------------------------------------------
__global__ __launch_bounds__(64) void pair_kernel(
    const float* __restrict__ x, const float2* __restrict__ tab,
    float* __restrict__ vout, float* __restrict__ Pout) {
  int row  = blockIdx.x;          // 0..8191
  int b    = row >> 8;
  int i    = row & 255;
  int lane = threadIdx.x;         // 0..63

  const float* xb = x + b * (NN * DD);
  float xi0 = xb[i * 3 + 0];
  float xi1 = xb[i * 3 + 1];
  float xi2 = xb[i * 3 + 2];

  float vx = 0.f, vy = 0.f, vz = 0.f, tr = 0.f;

#pragma unroll
  for (int q = 0; q < 4; ++q) {
    int j = lane + q * 64;
    if (j == i) continue;
    float r0  = xi0 - xb[j * 3 + 0];
    float r1  = xi1 - xb[j * 3 + 1];
    float r2  = xi2 - xb[j * 3 + 2];
    float dot = fmaf(r0, r0, fmaf(r1, r1, r2 * r2));
    float d   = sqrtf(dot + EPS);

    float s = d * INV_DX;
    int   k = (int)s;
    if (k > TABN - 2) k = TABN - 2;
    float uu = s - (float)k;

    float2 t0 = tab[k];
    float2 t1 = tab[k + 1];
    float  m0 = t0.y * DX, m1 = t1.y * DX;   // derivatives scaled to u-space
    float  u2 = uu * uu, u3 = u2 * uu;

    float h00 = 2.f * u3 - 3.f * u2 + 1.f;
    float h10 = u3 - 2.f * u2 + uu;
    float h11 = u3 - u2;
    float f   = h00 * (t0.x - t1.x) + t1.x + h10 * m0 + h11 * m1;

    float dh00 = 6.f * u2 - 6.f * uu;
    float dh10 = 3.f * u2 - 4.f * uu + 1.f;
    float dh11 = 3.f * u2 - 2.f * uu;
    float fp   = (dh00 * (t0.x - t1.x) + dh10 * m0 + dh11 * m1) * INV_DX;

    vx = fmaf(r0, f, vx);
    vy = fmaf(r1, f, vy);
    vz = fmaf(r2, f, vz);
    tr += fmaf(dot / d, fp, 3.f * f);
  }

#pragma unroll
  for (int off = 1; off < 64; off <<= 1) {
    vx += __shfl_xor(vx, off, 64);
    vy += __shfl_xor(vy, off, 64);
    vz += __shfl_xor(vz, off, 64);
    tr += __shfl_xor(tr, off, 64);
  }
  if (lane == 0) {
    const float inv = 1.f / (float)(NN - 1);
    vout[row * 3 + 0] = vx * inv;
    vout[row * 3 + 1] = vy * inv;
    vout[row * 3 + 2] = vz * inv;
    Pout[row] = tr;
  }
}

// ---------------------------------------------------------------------------
// Kernel 3: per-batch mean-subtract (y = v - mean_i v) and trace reduce.
// ---------------------------------------------------------------------------
__global__ __launch_bounds__(256) void finalize_kernel(
    const float* __restrict__ v, const float* __restrict__ P,
    float* __restrict__ out) {
  int b   = blockIdx.x;
  int i   = threadIdx.x;
  int row = b * NN + i;

  float v0 = v[row * 3 + 0];
  float v1 = v[row * 3 + 1];
  float v2 = v[row * 3 + 2];
  float p  = P[row];

  float s0 = v0, s1 = v1, s2 = v2, sp = p;
#pragma unroll
  for (int off = 1; off < 64; off <<= 1) {
    s0 += __shfl_xor(s0, off, 64);
    s1 += __shfl_xor(s1, off, 64);
    s2 += __shfl_xor(s2, off, 64);
    sp += __shfl_xor(sp, off, 64);
  }

  __shared__ float red[4][4];
  int w = i >> 6;
  if ((i & 63) == 0) { red[0][w] = s0; red[1][w] = s1; red[2][w] = s2; red[3][w] = sp; }
  __syncthreads();

  float t0 = (red[0][0] + red[0][1]) + (red[0][2] + red[0][3]);
  float t1 = (red[1][0] + red[1][1]) + (red[1][2] + red[1][3]);
  float t2 = (red[2][0] + red[2][1]) + (red[2][2] + red[2][3]);
  const float invN = 1.f / (float)NN;

  out[b * (NN * DD) + i * 3 + 0] = v0 - t0 * invN;
  out[b * (NN * DD) + i * 3 + 1] = v1 - t1 * invN;
  out[b * (NN * DD) + i * 3 + 2] = v2 - t2 * invN;

  if (i == 0) {
    float tp = (red[3][0] + red[3][1]) + (red[3][2] + red[3][3]);
    out[BB * NN * DD + b] = tp * invN;  // trace_b = (1/N) * sum_{i!=j}(3f + |r|^2 f'/d)
  }
}

// ---------------------------------------------------------------------------
extern "C" void kernel_launch(void* const* d_in, const int* in_sizes, int n_in,
                              void* d_out, int out_size, void* d_ws, size_t ws_size,
                              hipStream_t stream) {
  const float* t  = (const float*)d_in[0];
  const float* x  = (const float*)d_in[1];
  const float* W1 = (const float*)d_in[2];
  const float* b1 = (const float*)d_in[3];
  const float* W2 = (const float*)d_in[4];
  const float* b2 = (const float*)d_in[5];
  const float* W3 = (const float*)d_in[6];
  const float* b3 = (const float*)d_in[7];

  char*   ws  = (char*)d_ws;   // needs 147456 B total
  float2* tab = (float2*)ws;
  float*  v   = (float*)(ws + WS_V_OFF);
  float*  P   = (float*)(ws + WS_P_OFF);
  float*  out = (float*)d_out;

  hipLaunchKernelGGL(build_table_kernel, dim3(TABN * 8 / 256), dim3(256), 0, stream,
                     W1, b1, W2, b2, W3, b3, t, tab);
  hipLaunchKernelGGL(pair_kernel, dim3(BB * NN), dim3(64), 0, stream, x, tab, v, P);
  hipLaunchKernelGGL(finalize_kernel, dim3(BB), dim3(256), 0, stream, v, P, out);
}